// Round 14
// baseline (316.317 us; speedup 1.0000x reference)
//
#include <hip/hip_runtime.h>
#include <hip/hip_fp16.h>

// LFM2 short-conv block. Round 14: BK=32, 4 LDS buffers, 2 phases/tile, ONE
// barrier+vmcnt per tile, WAR-free fragment register rotation (fits 128 arch VGPR).
// Mechanism: waves pass s_barrier with MFMAs in flight; next phase's ds_reads target
// DIFFERENT registers -> matrix pipe drains under the LDS burst (true overlap).

typedef _Float16 f16x8 __attribute__((ext_vector_type(8)));
typedef float    f32x4 __attribute__((ext_vector_type(4)));

#define GLD_LDS16(gsrc, sdst) \
  __builtin_amdgcn_global_load_lds((const __attribute__((address_space(1))) void*)(gsrc), \
                                   (__attribute__((address_space(3))) void*)(sdst), 16, 0, 0)

#define VMCNT4 asm volatile("s_waitcnt vmcnt(4)" ::: "memory")
#define VMCNT0 asm volatile("s_waitcnt vmcnt(0)" ::: "memory")
#define LGKM0  asm volatile("s_waitcnt lgkmcnt(0)" ::: "memory")
#define BAR    __builtin_amdgcn_s_barrier()
#define SCHED0 __builtin_amdgcn_sched_barrier(0)
#define FENCE  asm volatile("" ::: "memory")

// ---------------- fused fp32 -> fp16 convert of X, W_in, W_out ----------------
__global__ __launch_bounds__(256) void cvt_all(const float* __restrict__ X,
                                               const float* __restrict__ Wi,
                                               const float* __restrict__ Wo,
                                               _Float16* __restrict__ Xh,
                                               _Float16* __restrict__ Wih,
                                               _Float16* __restrict__ Woh) {
  int base = (blockIdx.x * 256 + threadIdx.x) * 8;   // total 33,554,432 elems
  const float* src;
  _Float16* dst;
  int off;
  if (base < 16777216)      { src = X;  dst = Xh;  off = base; }
  else if (base < 29360128) { src = Wi; dst = Wih; off = base - 16777216; }
  else                      { src = Wo; dst = Woh; off = base - 29360128; }
  const float4* p = reinterpret_cast<const float4*>(src + off);
  float4 a = p[0], b = p[1];
  f16x8 o;
  o[0] = (_Float16)a.x; o[1] = (_Float16)a.y; o[2] = (_Float16)a.z; o[3] = (_Float16)a.w;
  o[4] = (_Float16)b.x; o[5] = (_Float16)b.y; o[6] = (_Float16)b.z; o[7] = (_Float16)b.w;
  *reinterpret_cast<f16x8*>(dst + off) = o;
}

// ---------------- conv + gating: y = Cg * causal_conv3(Bg * x) ----------------
__global__ __launch_bounds__(256) void conv_gate(const _Float16* __restrict__ BCx,
                                                 const float* __restrict__ Wc,   // [2048,1,3]
                                                 _Float16* __restrict__ Y) {
  const int h0 = threadIdx.x * 8;
  const int r0 = blockIdx.x * 8;
  const int s0 = r0 & 4095;

  float w0[8], w1[8], w2[8];
#pragma unroll
  for (int j = 0; j < 8; ++j) {
    w0[j] = Wc[(h0 + j) * 3 + 0];
    w1[j] = Wc[(h0 + j) * 3 + 1];
    w2[j] = Wc[(h0 + j) * 3 + 2];
  }

  float bxm2[8] = {}, bxm1[8] = {};
  if (s0 != 0) {
    const _Float16* pm2 = BCx + (size_t)(r0 - 2) * 6144 + h0;
    const _Float16* pm1 = BCx + (size_t)(r0 - 1) * 6144 + h0;
    f16x8 bg2 = *reinterpret_cast<const f16x8*>(pm2);
    f16x8 xx2 = *reinterpret_cast<const f16x8*>(pm2 + 4096);
    f16x8 bg1 = *reinterpret_cast<const f16x8*>(pm1);
    f16x8 xx1 = *reinterpret_cast<const f16x8*>(pm1 + 4096);
#pragma unroll
    for (int j = 0; j < 8; ++j) {
      bxm2[j] = (float)bg2[j] * (float)xx2[j];
      bxm1[j] = (float)bg1[j] * (float)xx1[j];
    }
  }

  for (int i = 0; i < 8; ++i) {
    const _Float16* pr = BCx + (size_t)(r0 + i) * 6144 + h0;
    f16x8 bg = *reinterpret_cast<const f16x8*>(pr);
    f16x8 cg = *reinterpret_cast<const f16x8*>(pr + 2048);
    f16x8 xx = *reinterpret_cast<const f16x8*>(pr + 4096);
    f16x8 o;
#pragma unroll
    for (int j = 0; j < 8; ++j) {
      float bx   = (float)bg[j] * (float)xx[j];
      float conv = w0[j] * bxm2[j] + w1[j] * bxm1[j] + w2[j] * bx;
      o[j] = (_Float16)((float)cg[j] * conv);
      bxm2[j] = bxm1[j];
      bxm1[j] = bx;
    }
    *reinterpret_cast<f16x8*>(Y + (size_t)(r0 + i) * 2048 + h0) = o;
  }
}

// ---------------- fragment helpers (BK=32: one f16x8 per fragment) ----------------
__device__ __forceinline__ void ldA4(f16x8 (&a)[4], const _Float16* p) {
#pragma unroll
  for (int i = 0; i < 4; ++i) a[i] = *(const f16x8*)(p + i * 512);
}
__device__ __forceinline__ void ldB2(f16x8 (&b)[2], const _Float16* p) {
#pragma unroll
  for (int j = 0; j < 2; ++j) b[j] = *(const f16x8*)(p + j * 512);
}
// half QM: Q(QM,0) then Q(QM,1) for QM=0; Q(QM,1) then Q(QM,0) for QM=1 (b-half reuse)
template <int QM>
__device__ __forceinline__ void mfmaHalf(f32x4 (&acc)[8][4], const f16x8 (&a)[4],
                                         const f16x8 (&b0)[2], const f16x8 (&b1)[2]) {
  __builtin_amdgcn_s_setprio(1);
#pragma unroll
  for (int i = 0; i < 4; ++i)
#pragma unroll
    for (int j = 0; j < 2; ++j)
      acc[QM * 4 + i][j] = __builtin_amdgcn_mfma_f32_16x16x32_f16(a[i], b0[j], acc[QM * 4 + i][j], 0, 0, 0);
#pragma unroll
  for (int i = 0; i < 4; ++i)
#pragma unroll
    for (int j = 0; j < 2; ++j)
      acc[QM * 4 + i][2 + j] = __builtin_amdgcn_mfma_f32_16x16x32_f16(a[i], b1[j], acc[QM * 4 + i][2 + j], 0, 0, 0);
  __builtin_amdgcn_s_setprio(0);
}

// 256x256 NT GEMM, BK=32, 8 waves (2x4), 16x16x32 MFMA, 128KB static LDS (4 buffers).
// LDS tile [256 rows][32 k] fp16 = 64B rows, 4 x 16B chunks; swizzle: phys chunk =
// logical ^ ((row>>1)&3)  [derived: 2-way bank spread for 16-lane groups; the
// row&3 form used at BK=64 degenerates to 4-way here]. gld_lds linear dest +
// inverse-swizzled per-lane SOURCE (rule 21).
// Per tile: Ph0 {read afL(4),bf0(2),bf1(2); stage A'(t+2)x2; lgkm0; Q00,Q01}
//           Ph1 {read afH(4);               stage B'(t+2)x2; lgkm0; Q11,Q10}
//           vmcnt(4); BAR   <- ONE barrier/tile; retires t+1's 4 DMAs (aged 1 tile)
// WAR-freedom: Ph-reads never target regs read by in-flight MFMAs (afL/afH split;
// bf parity sets alternate per tile) -> matrix pipe drains under next LDS burst.
// Overwrite audit: stage into buf (t+2)%4, last read at tile t-2, >=2 barriers prior.
// ARGS: N = C column stride, K = reduction dim, nbn = N/256. nt must be %4==0.
template <typename CT>
__global__ __launch_bounds__(512, 2) void gemm32(const _Float16* __restrict__ Ag,
                                                 const _Float16* __restrict__ Bg,
                                                 CT* __restrict__ Cg,
                                                 int N, int K, int nbn) {
  __shared__ __align__(16) _Float16 smem[65536];   // 128 KB
  const int tid = threadIdx.x, lane = tid & 63, w = tid >> 6;
  const int wr = w >> 2, wc = w & 3;

  // T1: XCD-bijective block swizzle (grid % 8 == 0)
  const int nwg = (int)gridDim.x, q8 = nwg >> 3;
  const int swz = ((int)blockIdx.x & 7) * q8 + ((int)blockIdx.x >> 3);
  const int bm = (swz / nbn) << 8, bn = (swz % nbn) << 8;

  // staging: thread covers 16B chunk (tid&3) of unit row (tid>>2); unit = 128 rows
  const int sCol = ((tid & 3) ^ ((tid >> 3) & 3)) * 8;      // inverse-swizzled source
  const _Float16* aSrc = Ag + (size_t)(bm + (tid >> 2)) * K + sCol;
  const _Float16* bSrc = Bg + (size_t)(bn + (tid >> 2)) * K + sCol;

  // read-side: phys chunk = (lane>>4) ^ ((row>>1)&3), row = lane&15 (+16-multiples)
  const int akc = (((lane >> 4) ^ ((lane >> 1) & 3))) * 8;
  const int aoff = (wr * 128 + (lane & 15)) * 32 + akc;     // afL; afH: +2048
  const int boff = (wc * 64 + (lane & 15)) * 32 + akc;      // bf0; bf1: +1024

  const int nt = K >> 5;

  // fp16-unit LDS bases: A buf k @ k*8192; B buf k @ 32768 + k*8192
#define STG_A(BUF, kt, u) GLD_LDS16(aSrc + (size_t)(u) * 128 * K + (kt) * 32, \
                                    (char*)smem + (BUF) * 16384 + (u) * 8192 + tid * 16)
#define STG_B(BUF, kt, u) GLD_LDS16(bSrc + (size_t)(u) * 128 * K + (kt) * 32, \
                                    (char*)smem + 65536 + (BUF) * 16384 + (u) * 8192 + tid * 16)

  f16x8 afL[4], afH[4];
  f16x8 bfE0[2], bfE1[2], bfO0[2], bfO1[2];   // bf sets alternate by tile parity
  f32x4 acc[8][4] = {};

  // prologue: stage tiles 0 -> buf0 and 1 -> buf1 (FIFO: t0's 4 first)
  STG_A(0, 0, 0); STG_A(0, 0, 1); STG_B(0, 0, 0); STG_B(0, 0, 1);
  STG_A(1, 1, 0); STG_A(1, 1, 1); STG_B(1, 1, 0); STG_B(1, 1, 1);
  VMCNT4; BAR; FENCE;   // retires t0's 4 -> buf0 readable

#define TILE(RB, SB, t, BF0, BF1)                                    \
  {                                                                  \
    const int tn = ((t) + 2 < nt) ? (t) + 2 : nt - 1;                \
    const _Float16* Ab = smem + (RB) * 8192;                         \
    const _Float16* Bb = smem + 32768 + (RB) * 8192;                 \
    /* Ph0 */                                                        \
    ldA4(afL, Ab + aoff);                                            \
    ldB2(BF0, Bb + boff);                                            \
    ldB2(BF1, Bb + boff + 1024);                                     \
    STG_A(SB, tn, 0); STG_A(SB, tn, 1);                              \
    LGKM0; SCHED0;                                                   \
    mfmaHalf<0>(acc, afL, BF0, BF1);                                 \
    /* Ph1 */                                                        \
    ldA4(afH, Ab + aoff + 2048);                                     \
    STG_B(SB, tn, 0); STG_B(SB, tn, 1);                              \
    LGKM0; SCHED0;                                                   \
    mfmaHalf<1>(acc, afH, BF0, BF1);                                 \
    VMCNT4; BAR; FENCE;                                              \
  }

  for (int t = 0; t < nt; t += 4) {
    TILE(0, 2, t,     bfE0, bfE1);
    TILE(1, 3, t + 1, bfO0, bfO1);
    TILE(2, 0, t + 2, bfE0, bfE1);
    TILE(3, 1, t + 3, bfO0, bfO1);
  }
  VMCNT0;  // drain harmless tail restages

  // epilogue: D row=(lane>>4)*4+reg, col=lane&15
  const int rb = bm + wr * 128 + ((lane >> 4) << 2);
  const int cb = bn + wc * 64 + (lane & 15);
#pragma unroll
  for (int mi = 0; mi < 8; ++mi)
#pragma unroll
    for (int nj = 0; nj < 4; ++nj) {
      f32x4 v = acc[mi][nj];
#pragma unroll
      for (int rg = 0; rg < 4; ++rg)
        Cg[(size_t)(rb + mi * 16 + rg) * N + cb + nj * 16] = (CT)v[rg];
    }
#undef TILE
#undef STG_A
#undef STG_B
}

// ---------------- launcher ----------------
extern "C" void kernel_launch(void* const* d_in, const int* in_sizes, int n_in,
                              void* d_out, int out_size, void* d_ws, size_t ws_size,
                              hipStream_t stream) {
  const float* X  = (const float*)d_in[0];  // [2,4096,2048]
  const float* Wi = (const float*)d_in[1];  // [6144,2048]
  const float* Wc = (const float*)d_in[2];  // [2048,1,3]
  const float* Wo = (const float*)d_in[3];  // [2048,2048]
  float* out = (float*)d_out;               // [2,4096,2048] fp32

  char* ws = (char*)d_ws;
  _Float16* Xh   = (_Float16*)(ws);                    // 33,554,432 B
  _Float16* Wih  = (_Float16*)(ws + 33554432);         // 25,165,824 B
  _Float16* Woh  = (_Float16*)(ws + 58720256);         //  8,388,608 B
  _Float16* BCxh = (_Float16*)(ws + 67108864);         // 100,663,296 B
  _Float16* Yh   = (_Float16*)(ws + 167772160);        // 33,554,432 B
  (void)ws_size; (void)in_sizes; (void)n_in; (void)out_size;

  cvt_all<<<dim3(16384), 256, 0, stream>>>(X, Wi, Wo, Xh, Wih, Woh);

  // in_proj: [8192,2048] x [6144,2048]^T -> BCx fp16   (32 x 24 = 768 blocks)
  gemm32<_Float16><<<dim3(768), 512, 0, stream>>>(Xh, Wih, BCxh, 6144, 2048, 24);

  conv_gate<<<dim3(1024), 256, 0, stream>>>(BCxh, Wc, Yh);

  // out_proj: [8192,2048] x [2048,2048]^T -> out fp32  (32 x 8 = 256 blocks; N=2048)
  gemm32<float><<<dim3(256), 512, 0, stream>>>(Yh, Woh, out, 2048, 2048, 8);
}

// Round 15
// 293.403 us; speedup vs baseline: 1.0781x; 1.0781x over previous
//
#include <hip/hip_runtime.h>
#include <hip/hip_fp16.h>

// LFM2 short-conv block. Round 15: r13 GEMM core unchanged; W_in rows permuted at
// cvt (col 2h=Bg_h, 2h+1=x_h; Cg at cols 4096+) so GEMM1's epilogue computes
// Bx=Bg*x via __shfl_xor(v,1) and writes Bx(32MB)+Cg(32MB) instead of BCx(100MB).
// conv reads 67MB instead of 100MB. Schedule family exhausted at 180us (r5-r14).

typedef _Float16 f16x8 __attribute__((ext_vector_type(8)));
typedef float    f32x4 __attribute__((ext_vector_type(4)));

#define GLD_LDS16(gsrc, sdst) \
  __builtin_amdgcn_global_load_lds((const __attribute__((address_space(1))) void*)(gsrc), \
                                   (__attribute__((address_space(3))) void*)(sdst), 16, 0, 0)

#define VMCNT4 asm volatile("s_waitcnt vmcnt(4)" ::: "memory")
#define VMCNT0 asm volatile("s_waitcnt vmcnt(0)" ::: "memory")
#define LGKM0  asm volatile("s_waitcnt lgkmcnt(0)" ::: "memory")
#define BAR    __builtin_amdgcn_s_barrier()
#define FENCE  asm volatile("" ::: "memory")   // compiler-only; no instruction

// ---------------- fused fp32 -> fp16 convert; W_in rows PERMUTED ----------------
// Permutation (dst row of Wih): src row r<2048 (Bg_h)   -> 2r
//                               2048<=r<4096 (Cg)      -> r+2048   (cols 4096+)
//                               r>=4096 (x_h)          -> 2(r-4096)+1
__global__ __launch_bounds__(256) void cvt_all(const float* __restrict__ X,
                                               const float* __restrict__ Wi,
                                               const float* __restrict__ Wo,
                                               _Float16* __restrict__ Xh,
                                               _Float16* __restrict__ Wih,
                                               _Float16* __restrict__ Woh) {
  int base = (blockIdx.x * 256 + threadIdx.x) * 8;   // total 33,554,432 elems
  const float* src;
  _Float16* dst;
  if (base < 16777216) {
    src = X + base; dst = Xh + base;
  } else if (base < 29360128) {
    int off = base - 16777216;
    int row = off >> 11, col = off & 2047;
    int rd = (row < 2048) ? (row << 1) : (row < 4096 ? row + 2048 : (((row - 4096) << 1) | 1));
    src = Wi + off; dst = Wih + rd * 2048 + col;
  } else {
    int off = base - 29360128;
    src = Wo + off; dst = Woh + off;
  }
  const float4* p = reinterpret_cast<const float4*>(src);
  float4 a = p[0], b = p[1];
  f16x8 o;
  o[0] = (_Float16)a.x; o[1] = (_Float16)a.y; o[2] = (_Float16)a.z; o[3] = (_Float16)a.w;
  o[4] = (_Float16)b.x; o[5] = (_Float16)b.y; o[6] = (_Float16)b.z; o[7] = (_Float16)b.w;
  *reinterpret_cast<f16x8*>(dst) = o;
}

// ---------------- conv + Cg gating: y = Cg * causal_conv3(Bx) ----------------
__global__ __launch_bounds__(256) void conv_gate2(const _Float16* __restrict__ Bx,
                                                  const _Float16* __restrict__ Cgb,
                                                  const float* __restrict__ Wc,   // [2048,1,3]
                                                  _Float16* __restrict__ Y) {
  const int h0 = threadIdx.x * 8;
  const int r0 = blockIdx.x * 8;
  const int s0 = r0 & 4095;

  float w0[8], w1[8], w2[8];
#pragma unroll
  for (int j = 0; j < 8; ++j) {
    w0[j] = Wc[(h0 + j) * 3 + 0];
    w1[j] = Wc[(h0 + j) * 3 + 1];
    w2[j] = Wc[(h0 + j) * 3 + 2];
  }

  float bxm2[8] = {}, bxm1[8] = {};
  if (s0 != 0) {
    f16x8 b2 = *reinterpret_cast<const f16x8*>(Bx + (size_t)(r0 - 2) * 2048 + h0);
    f16x8 b1 = *reinterpret_cast<const f16x8*>(Bx + (size_t)(r0 - 1) * 2048 + h0);
#pragma unroll
    for (int j = 0; j < 8; ++j) { bxm2[j] = (float)b2[j]; bxm1[j] = (float)b1[j]; }
  }

  for (int i = 0; i < 8; ++i) {
    f16x8 bxv = *reinterpret_cast<const f16x8*>(Bx  + (size_t)(r0 + i) * 2048 + h0);
    f16x8 cgv = *reinterpret_cast<const f16x8*>(Cgb + (size_t)(r0 + i) * 2048 + h0);
    f16x8 o;
#pragma unroll
    for (int j = 0; j < 8; ++j) {
      float bx   = (float)bxv[j];
      float conv = w0[j] * bxm2[j] + w1[j] * bxm1[j] + w2[j] * bx;
      o[j] = (_Float16)((float)cgv[j] * conv);
      bxm2[j] = bxm1[j];
      bxm1[j] = bx;
    }
    *reinterpret_cast<f16x8*>(Y + (size_t)(r0 + i) * 2048 + h0) = o;
  }
}

// ---------------- fragment load helpers ----------------
__device__ __forceinline__ void ldA(f16x8 (&af)[4][2], const _Float16* p, int base, int ak0, int ak1) {
#pragma unroll
  for (int i = 0; i < 4; ++i) {
    af[i][0] = *(const f16x8*)(p + base + i * 1024 + ak0);
    af[i][1] = *(const f16x8*)(p + base + i * 1024 + ak1);
  }
}
__device__ __forceinline__ void ldB(f16x8 (&bf)[2][2], const _Float16* p, int base, int ak0, int ak1) {
#pragma unroll
  for (int j = 0; j < 2; ++j) {
    bf[j][0] = *(const f16x8*)(p + base + j * 1024 + ak0);
    bf[j][1] = *(const f16x8*)(p + base + j * 1024 + ak1);
  }
}
template <int QM, int QN>
__device__ __forceinline__ void mfmaQ(f32x4 (&acc)[8][4], const f16x8 (&af)[4][2], const f16x8 (&bf)[2][2]) {
  __builtin_amdgcn_s_setprio(1);
#pragma unroll
  for (int i = 0; i < 4; ++i)
#pragma unroll
    for (int j = 0; j < 2; ++j)
#pragma unroll
      for (int ks = 0; ks < 2; ++ks)
        acc[QM * 4 + i][QN * 2 + j] =
            __builtin_amdgcn_mfma_f32_16x16x32_f16(af[i][ks], bf[j][ks], acc[QM * 4 + i][QN * 2 + j], 0, 0, 0);
  __builtin_amdgcn_s_setprio(0);
}

// 256x256 NT GEMM (r13 core). MODE 0: plain CT stores to Cg_out (stride N).
// MODE 1 (GEMM1): bn<4096 -> paired Bg/x cols: Bx = v * shfl_xor(v,1), even lanes
// store fp16 to BxP[row][col/2]; bn>=4096 -> store fp16 Cg to CgP[row][col-4096].
template <typename CT, int MODE>
__global__ __launch_bounds__(512, 2) void gemm8p(const _Float16* __restrict__ Ag,
                                                 const _Float16* __restrict__ Bg,
                                                 CT* __restrict__ Cg_out,
                                                 _Float16* __restrict__ BxP,
                                                 _Float16* __restrict__ CgP,
                                                 int N, int K, int nbn) {
  __shared__ __align__(16) char smem[131072];
  const int tid = threadIdx.x, lane = tid & 63, w = tid >> 6;
  const int wr = w >> 2, wc = w & 3;

  // T1: XCD-bijective block swizzle (grid % 8 == 0)
  const int nwg = (int)gridDim.x, q8 = nwg >> 3;
  const int swz = ((int)blockIdx.x & 7) * q8 + ((int)blockIdx.x >> 3);
  const int bm = (swz / nbn) << 8, bn = (swz % nbn) << 8;

  _Float16* const A0 = (_Float16*)(smem);
  _Float16* const B0 = (_Float16*)(smem + 32768);
  _Float16* const A1 = (_Float16*)(smem + 65536);
  _Float16* const B1 = (_Float16*)(smem + 98304);

  const int rr = tid >> 3;
  const int sCol = ((tid & 7) ^ (rr & 7)) * 8;                  // inverse-swizzled source chunk
  const _Float16* aSrc = Ag + (size_t)(bm + rr) * K + sCol;
  const _Float16* bSrc = Bg + (size_t)(bn + (rr >> 5) * 64 + (rr & 31)) * K + sCol;

  const int ak0 = ((lane >> 4) ^ (lane & 7)) * 8;
  const int ak1 = (((lane >> 4) + 4) ^ (lane & 7)) * 8;
  const int aRB = (wr * 128 + (lane & 15)) * 64;
  const int bRB = (wc * 32 + (lane & 15)) * 64;

  const int nt = K >> 6;

#define STG_A(NBO, kt, u) GLD_LDS16(aSrc + (size_t)(u) * 64 * K + (kt) * 64, \
                                    smem + (NBO) + (u) * 8192 + tid * 16)
#define STG_B(NBO, kt, u) GLD_LDS16(bSrc + (size_t)(((u) & 1) * 128 + ((u) >> 1) * 32) * K + (kt) * 64, \
                                    smem + (NBO) + 32768 + (u) * 8192 + tid * 16)

  f16x8 af[4][2], bf[2][2];
  f32x4 acc[8][4] = {};

  STG_A(0, 0, 0); STG_A(0, 0, 2);
  STG_B(0, 0, 0); STG_B(0, 0, 1);
  STG_B(0, 0, 2); STG_B(0, 0, 3);
  STG_A(0, 0, 1); STG_A(0, 0, 3);
  VMCNT4; BAR; FENCE;

#define TILE(AB, BB, NBO, t)                                       \
  {                                                                \
    const int tn = ((t) + 1 < nt) ? (t) + 1 : nt - 1;              \
    ldA(af, AB, aRB, ak0, ak1);                                    \
    ldB(bf, BB, bRB, ak0, ak1);                                    \
    STG_A(NBO, tn, 0); STG_A(NBO, tn, 2);                          \
    VMCNT4; BAR; FENCE;                                            \
    mfmaQ<0, 0>(acc, af, bf);                                      \
    ldB(bf, BB, bRB + 8192, ak0, ak1);                             \
    STG_B(NBO, tn, 0); STG_B(NBO, tn, 1);                          \
    VMCNT4; BAR; FENCE;                                            \
    mfmaQ<0, 1>(acc, af, bf);                                      \
    ldA(af, AB, aRB + 4096, ak0, ak1);                             \
    STG_B(NBO, tn, 2); STG_B(NBO, tn, 3);                          \
    BAR; FENCE;                                                    \
    mfmaQ<1, 1>(acc, af, bf);                                      \
    ldB(bf, BB, bRB, ak0, ak1);                                    \
    STG_A(NBO, tn, 1); STG_A(NBO, tn, 3);                          \
    VMCNT4; BAR; FENCE;                                            \
    mfmaQ<1, 0>(acc, af, bf);                                      \
  }

  for (int t = 0; t < nt; t += 2) {
    TILE(A0, B0, 65536, t);
    TILE(A1, B1, 0, t + 1);
  }
  LGKM0; VMCNT0;

  // epilogue: D row=(lane>>4)*4+reg, col=lane&15
  const int rb  = bm + wr * 128 + ((lane >> 4) << 2);
  const int cbl = bn + wc * 64 + (lane & 15);
  if (MODE == 0) {
#pragma unroll
    for (int mi = 0; mi < 8; ++mi)
#pragma unroll
      for (int nj = 0; nj < 4; ++nj) {
        f32x4 v = acc[mi][nj];
#pragma unroll
        for (int rg = 0; rg < 4; ++rg)
          Cg_out[(size_t)(rb + mi * 16 + rg) * N + cbl + nj * 16] = (CT)v[rg];
      }
  } else if (bn < 4096) {
    // paired region: col 2h = Bg_h, 2h+1 = x_h (lane parity = col parity)
    const bool writer = ((lane & 1) == 0);
#pragma unroll
    for (int mi = 0; mi < 8; ++mi)
#pragma unroll
      for (int nj = 0; nj < 4; ++nj) {
        f32x4 v = acc[mi][nj];
        const int h = (cbl + nj * 16) >> 1;
#pragma unroll
        for (int rg = 0; rg < 4; ++rg) {
          float part = __shfl_xor(v[rg], 1);
          float p = v[rg] * part;
          if (writer)
            BxP[(size_t)(rb + mi * 16 + rg) * 2048 + h] = (_Float16)p;
        }
      }
  } else {
    const int hc = cbl - 4096;
#pragma unroll
    for (int mi = 0; mi < 8; ++mi)
#pragma unroll
      for (int nj = 0; nj < 4; ++nj) {
        f32x4 v = acc[mi][nj];
#pragma unroll
        for (int rg = 0; rg < 4; ++rg)
          CgP[(size_t)(rb + mi * 16 + rg) * 2048 + hc + nj * 16] = (_Float16)v[rg];
      }
  }
#undef TILE
#undef STG_A
#undef STG_B
}

// ---------------- launcher ----------------
extern "C" void kernel_launch(void* const* d_in, const int* in_sizes, int n_in,
                              void* d_out, int out_size, void* d_ws, size_t ws_size,
                              hipStream_t stream) {
  const float* X  = (const float*)d_in[0];  // [2,4096,2048]
  const float* Wi = (const float*)d_in[1];  // [6144,2048]
  const float* Wc = (const float*)d_in[2];  // [2048,1,3]
  const float* Wo = (const float*)d_in[3];  // [2048,2048]
  float* out = (float*)d_out;               // [2,4096,2048] fp32

  char* ws = (char*)d_ws;
  _Float16* Xh  = (_Float16*)(ws);                     // 33,554,432 B
  _Float16* Wih = (_Float16*)(ws + 33554432);          // 25,165,824 B (permuted rows)
  _Float16* Woh = (_Float16*)(ws + 58720256);          //  8,388,608 B
  _Float16* Bx  = (_Float16*)(ws + 67108864);          // 33,554,432 B
  _Float16* CgB = (_Float16*)(ws + 100663296);         // 33,554,432 B
  _Float16* Yh  = (_Float16*)(ws + 134217728);         // 33,554,432 B -> 167,772,160 total
  (void)ws_size; (void)in_sizes; (void)n_in; (void)out_size;

  cvt_all<<<dim3(16384), 256, 0, stream>>>(X, Wi, Wo, Xh, Wih, Woh);

  // in_proj (+gate fusion): writes Bx[8192,2048] and Cg[8192,2048] fp16
  gemm8p<_Float16, 1><<<dim3(768), 512, 0, stream>>>(Xh, Wih, Bx, Bx, CgB, 6144, 2048, 24);

  conv_gate2<<<dim3(1024), 256, 0, stream>>>(Bx, CgB, Wc, Yh);

  // out_proj: [8192,2048] x [2048,2048]^T -> out fp32
  gemm8p<float, 0><<<dim3(256), 512, 0, stream>>>(Yh, Woh, out, nullptr, nullptr, 2048, 2048, 8);
}